// Round 3
// baseline (3816.220 us; speedup 1.0000x reference)
//
#include <hip/hip_runtime.h>

// WaveNet residual stack, MFMA bf16, single persistent cooperative kernel for
// the 40-block sequential chain (custom 2-level grid barrier), + deferred skip
// GEMM kernel. Residual stream fp32; matmul operands bf16.

#define CC    64
#define SCC   256
#define BB    4
#define LL0   8192
#define NBLK  40
#define SKIPN 4096
#define TT    64
#define NWG   512         // = BB * 128 tiles, co-resident at 2 blocks/CU
#define NGRP  32
#define GRPSZ 16          // NWG / NGRP
#define BARSTRIDE 544     // ints per step: 32 groups * 16 + root@512 + flag@528

typedef __attribute__((ext_vector_type(8))) short bf16x8;
typedef __attribute__((ext_vector_type(4))) float f32x4;

__device__ __forceinline__ unsigned short f2bf(float f) {
    union { float f; unsigned u; } v; v.f = f;
    return (unsigned short)((v.u + 0x7FFF + ((v.u >> 16) & 1)) >> 16);
}

// ---- weight prep: bf16 casts + dc-weight concat [o][kk] ----
__global__ __launch_bounds__(256) void prep_weights(
    const float* __restrict__ dc_w, const float* __restrict__ conv_w,
    const float* __restrict__ skip_w,
    unsigned short* __restrict__ wcat,  // [NBLK][64][128]
    unsigned short* __restrict__ cwb,   // [NBLK][64][64]
    unsigned short* __restrict__ swb)   // [NBLK][256][64]
{
    const int n_sw = NBLK * SCC * CC;
    const int n_cw = NBLK * CC * CC;
    const int n_wc = NBLK * CC * 128;
    for (int idx = blockIdx.x * blockDim.x + threadIdx.x; idx < n_sw;
         idx += gridDim.x * blockDim.x) {
        swb[idx] = f2bf(skip_w[idx]);
        if (idx < n_cw) cwb[idx] = f2bf(conv_w[idx]);
        if (idx < n_wc) {
            const int i = idx >> 13, o = (idx >> 7) & 63, kk = idx & 127;
            wcat[idx] = f2bf(dc_w[(((i * CC + o) * CC) + (kk & 63)) * 2 + (kk >> 6)]);
        }
    }
}

// ---- zero barrier slots (runs every launch; poison/replay-safe) ----
__global__ __launch_bounds__(256) void bar_init(int* __restrict__ bar) {
    const int n = NBLK * BARSTRIDE;
    for (int i = blockIdx.x * blockDim.x + threadIdx.x; i < n;
         i += gridDim.x * blockDim.x) bar[i] = 0;
}

// ---- two-level grid barrier (all NWG workgroups must call) ----
__device__ __forceinline__ void grid_barrier(int* bar, int step, int wg) {
    __builtin_amdgcn_fence(__ATOMIC_RELEASE, "agent");
    __syncthreads();
    if (threadIdx.x == 0) {
        int* base = bar + step * BARSTRIDE;
        const int g = wg >> 4;           // 32 groups of 16
        int old = __hip_atomic_fetch_add(base + g * 16, 1,
                                         __ATOMIC_RELAXED, __HIP_MEMORY_SCOPE_AGENT);
        if (old == GRPSZ - 1) {
            int r = __hip_atomic_fetch_add(base + 512, 1,
                                           __ATOMIC_RELAXED, __HIP_MEMORY_SCOPE_AGENT);
            if (r == NGRP - 1)
                __hip_atomic_store(base + 528, 1,
                                   __ATOMIC_RELAXED, __HIP_MEMORY_SCOPE_AGENT);
        }
        while (__hip_atomic_load(base + 528, __ATOMIC_RELAXED,
                                 __HIP_MEMORY_SCOPE_AGENT) == 0)
            __builtin_amdgcn_s_sleep(8);
    }
    __syncthreads();
    __builtin_amdgcn_fence(__ATOMIC_ACQUIRE, "agent");
}

// ---- one residual block's work for one (b, t0) tile ----
__device__ __forceinline__ void block_body(
    const float* __restrict__ cur, float* __restrict__ nxt,
    const unsigned short* __restrict__ wcat, const unsigned short* __restrict__ cwb,
    const float* __restrict__ db, const float* __restrict__ cb,
    unsigned short* __restrict__ g_out,
    int d, int Lin, int Lout, int b, int t0,
    unsigned short* xt, unsigned short* gs)
{
    const int tid  = threadIdx.x;
    const int lane = tid & 63;
    const int wv   = tid >> 6;
    const float* src = cur + (size_t)b * CC * LL0;

    // stage X0 (kk=c) / X1 (kk=64+c) fp32 -> bf16, transposed to [t][kk], swizzled
    {
        const int c  = (tid & 31) * 2;
        const int tg = tid >> 5;
        #pragma unroll
        for (int op = 0; op < 2; ++op) {
            const int doff = op ? d : 0;
            const int tb = t0 + tg * 8 + doff;
            float v0[8], v1[8];
            if (t0 + TT + d <= Lin && (d & 3) == 0) {
                *(float4*)&v0[0] = *(const float4*)(src + (size_t)c * LL0 + tb);
                *(float4*)&v0[4] = *(const float4*)(src + (size_t)c * LL0 + tb + 4);
                *(float4*)&v1[0] = *(const float4*)(src + (size_t)(c + 1) * LL0 + tb);
                *(float4*)&v1[4] = *(const float4*)(src + (size_t)(c + 1) * LL0 + tb + 4);
            } else {
                #pragma unroll
                for (int j = 0; j < 8; ++j) {
                    int t = tb + j; if (t > Lin - 1) t = Lin - 1;
                    v0[j] = src[(size_t)c * LL0 + t];
                    v1[j] = src[(size_t)(c + 1) * LL0 + t];
                }
            }
            const int kk = op * 64 + c;
            const int chunk = kk >> 3, sub = kk & 7;
            #pragma unroll
            for (int j = 0; j < 8; ++j) {
                const int row = tg * 8 + j;
                const unsigned pack = (unsigned)f2bf(v0[j]) | ((unsigned)f2bf(v1[j]) << 16);
                *(unsigned*)((char*)xt + row * 256 + ((chunk ^ (row & 7)) * 16) + sub * 2) = pack;
            }
        }
    }
    __syncthreads();

    // GEMM1: H = Xcat . Wcat^T (+db), relu -> gs
    bf16x8 a1[4];
    {
        const int row = wv * 16 + (lane & 15);
        #pragma unroll
        for (int ks = 0; ks < 4; ++ks) {
            const int chunk = ks * 4 + (lane >> 4);
            a1[ks] = *(const bf16x8*)((const char*)xt + row * 256 + ((chunk ^ (row & 7)) * 16));
        }
    }
    f32x4 acc[4];
    #pragma unroll
    for (int n = 0; n < 4; ++n) {
        const int o = n * 16 + (lane & 15);
        const float bias = db[o];
        acc[n] = (f32x4){bias, bias, bias, bias};
        const unsigned short* wrow = wcat + o * 128 + (lane >> 4) * 8;
        #pragma unroll
        for (int ks = 0; ks < 4; ++ks)
            acc[n] = __builtin_amdgcn_mfma_f32_16x16x32_bf16(
                a1[ks], *(const bf16x8*)(wrow + ks * 32), acc[n], 0, 0, 0);
    }
    {
        const int trow0 = wv * 16 + ((lane >> 4) << 2);
        #pragma unroll
        for (int n = 0; n < 4; ++n) {
            const int o = n * 16 + (lane & 15);
            const int chunkb = o >> 3, sub = o & 7;
            #pragma unroll
            for (int r = 0; r < 4; ++r) {
                float g = acc[n][r]; g = g > 0.f ? g : 0.f;
                const int row = trow0 + r;
                *(unsigned short*)((char*)gs + row * 128 + ((chunkb ^ (row & 7)) * 16) + sub * 2) = f2bf(g);
            }
        }
    }
    __syncthreads();

    // GEMM2 + residual + OUT store
    bf16x8 a2[2];
    {
        const int row = wv * 16 + (lane & 15);
        #pragma unroll
        for (int ks = 0; ks < 2; ++ks) {
            const int chunk = ks * 4 + (lane >> 4);
            a2[ks] = *(const bf16x8*)((const char*)gs + row * 128 + ((chunk ^ (row & 7)) * 16));
        }
    }
    {
        const int tloc = wv * 16 + ((lane >> 4) << 2);
        const int t = t0 + tloc;
        #pragma unroll
        for (int n = 0; n < 4; ++n) {
            const int o = n * 16 + (lane & 15);
            const float bias = cb[o];
            f32x4 racc = (f32x4){bias, bias, bias, bias};
            const unsigned short* wrow = cwb + o * 64 + (lane >> 4) * 8;
            racc = __builtin_amdgcn_mfma_f32_16x16x32_bf16(a2[0], *(const bf16x8*)(wrow), racc, 0, 0, 0);
            racc = __builtin_amdgcn_mfma_f32_16x16x32_bf16(a2[1], *(const bf16x8*)(wrow + 32), racc, 0, 0, 0);
            const float* resp = src + (size_t)o * LL0 + t + d;
            float* outp = nxt + (size_t)b * CC * LL0 + (size_t)o * LL0 + t;
            if (t + 3 < Lout && (d & 3) == 0) {
                const float4 x1 = *(const float4*)resp;
                *(float4*)outp = (float4){racc[0] + x1.x, racc[1] + x1.y,
                                          racc[2] + x1.z, racc[3] + x1.w};
            } else {
                #pragma unroll
                for (int r = 0; r < 4; ++r)
                    if (t + r < Lout) outp[r] = racc[r] + resp[r];
            }
        }
    }

    // store g window (bf16 [b][tw][64])
    {
        const int skip_start = Lout - SKIPN;
        const int row = tid >> 2;
        const int t = t0 + row;
        if (t >= skip_start && t < Lout) {
            unsigned short* gr = g_out + ((size_t)b * SKIPN + (t - skip_start)) * CC;
            #pragma unroll
            for (int q = 0; q < 2; ++q) {
                const int chunk = (tid & 3) * 2 + q;
                bf16x8 vv = *(const bf16x8*)((const char*)gs + row * 128 + ((chunk ^ (row & 7)) * 16));
                *(bf16x8*)(gr + chunk * 8) = vv;
            }
        }
    }
}

struct ChainParams {
    float* buf0; float* buf1;
    const unsigned short* wcat; const unsigned short* cwb;
    const float* dc_b; const float* conv_b;
    unsigned short* g_all;
    int* bar;
};

__global__ __launch_bounds__(256, 2) void chain_kernel(ChainParams p) {
    __shared__ __align__(16) unsigned short xt[TT * 128];
    __shared__ __align__(16) unsigned short gs[TT * CC];
    const int wg = blockIdx.x;
    const int b  = wg >> 7;
    const int tt = wg & 127;
    int Lc = LL0;
    for (int i = 0; i < NBLK; ++i) {
        const int d = 1 << (i % 10);
        const int Lout = Lc - d;
        const int ntiles = (Lout + TT - 1) / TT;
        const float* cur = (i & 1) ? p.buf1 : p.buf0;
        float*       nxt = (i & 1) ? p.buf0 : p.buf1;
        if (tt < ntiles)
            block_body(cur, nxt,
                       p.wcat + (size_t)i * CC * 128, p.cwb + (size_t)i * CC * CC,
                       p.dc_b + i * CC, p.conv_b + i * CC,
                       p.g_all + (size_t)i * BB * SKIPN * CC,
                       d, Lc, Lout, b, tt * TT, xt, gs);
        Lc = Lout;
        if (i != NBLK - 1) grid_barrier(p.bar, i, wg);
    }
}

// ---- deferred skip GEMMs ----
__global__ __launch_bounds__(256) void skip_kernel(
    const unsigned short* __restrict__ g_all,
    const unsigned short* __restrict__ swb,
    const float* __restrict__ skip_b,
    float* __restrict__ out)
{
    const int ntile = SKIPN / TT;
    const int tid = threadIdx.x, lane = tid & 63, wv = tid >> 6;
    int id = blockIdx.x;
    const int tt = id % ntile; id /= ntile;
    const int b  = id % BB;    id /= BB;
    const int blk = id;

    const unsigned short* g  = g_all + ((size_t)blk * BB + b) * SKIPN * CC;
    const unsigned short* sw = swb + (size_t)blk * SCC * CC;
    const float* sb = skip_b + blk * SCC;
    float* op = out + ((size_t)blk * BB + b) * SCC * SKIPN;

    const int trow = tt * TT + wv * 16 + (lane & 15);
    bf16x8 a[2];
    #pragma unroll
    for (int ks = 0; ks < 2; ++ks)
        a[ks] = *(const bf16x8*)(g + (size_t)trow * CC + ks * 32 + (lane >> 4) * 8);

    const int tstore = tt * TT + wv * 16 + ((lane >> 4) << 2);
    #pragma unroll 4
    for (int n = 0; n < 16; ++n) {
        const int sc = n * 16 + (lane & 15);
        const float bias = sb[sc];
        f32x4 acc = (f32x4){bias, bias, bias, bias};
        const unsigned short* wrow = sw + sc * CC + (lane >> 4) * 8;
        acc = __builtin_amdgcn_mfma_f32_16x16x32_bf16(a[0], *(const bf16x8*)(wrow), acc, 0, 0, 0);
        acc = __builtin_amdgcn_mfma_f32_16x16x32_bf16(a[1], *(const bf16x8*)(wrow + 32), acc, 0, 0, 0);
        *(float4*)(op + (size_t)sc * SKIPN + tstore) = (float4){acc[0], acc[1], acc[2], acc[3]};
    }
}

extern "C" void kernel_launch(void* const* d_in, const int* in_sizes, int n_in,
                              void* d_out, int out_size, void* d_ws, size_t ws_size,
                              hipStream_t stream)
{
    const float* x      = (const float*)d_in[0];
    const float* dc_w   = (const float*)d_in[1];
    const float* dc_b   = (const float*)d_in[2];
    const float* conv_w = (const float*)d_in[3];
    const float* conv_b = (const float*)d_in[4];
    const float* skip_w = (const float*)d_in[5];
    const float* skip_b = (const float*)d_in[6];
    float* out = (float*)d_out;

    char* ws = (char*)d_ws;
    float* buf0 = (float*)ws;                    ws += (size_t)BB * CC * LL0 * 4;
    float* buf1 = (float*)ws;                    ws += (size_t)BB * CC * LL0 * 4;
    unsigned short* g_all = (unsigned short*)ws; ws += (size_t)NBLK * BB * SKIPN * CC * 2;
    unsigned short* wcat  = (unsigned short*)ws; ws += (size_t)NBLK * CC * 128 * 2;
    unsigned short* cwb   = (unsigned short*)ws; ws += (size_t)NBLK * CC * CC * 2;
    unsigned short* swb   = (unsigned short*)ws; ws += (size_t)NBLK * SCC * CC * 2;
    int* bar = (int*)ws;                         ws += (size_t)NBLK * BARSTRIDE * 4;

    hipMemcpyAsync(buf0, x, (size_t)BB * CC * LL0 * sizeof(float),
                   hipMemcpyDeviceToDevice, stream);
    prep_weights<<<1024, 256, 0, stream>>>(dc_w, conv_w, skip_w, wcat, cwb, swb);
    bar_init<<<40, 256, 0, stream>>>(bar);

    ChainParams P{buf0, buf1, wcat, cwb, dc_b, conv_b, g_all, bar};
    void* args[] = {&P};
    hipLaunchCooperativeKernel((const void*)chain_kernel, dim3(NWG), dim3(256),
                               args, 0, stream);

    skip_kernel<<<dim3(NBLK * BB * (SKIPN / TT)), 256, 0, stream>>>(
        g_all, swb, skip_b, out);
}

// Round 4
// 853.094 us; speedup vs baseline: 4.4734x; 4.4734x over previous
//
#include <hip/hip_runtime.h>

// WaveNet residual stack, MFMA bf16. 40 per-block launches (proven faster than
// cooperative grid-sync on gfx950: agent fences cost ~85us/step vs ~22us
// relaunch). Launch i also carries block i-1's skip GEMM as extra workgroups
// (uses CUs idle during the latency-bound chain step). Residual stream fp32;
// matmul operands bf16.

#define CC    64
#define SCC   256
#define BB    4
#define LL0   8192
#define NBLK  40
#define SKIPN 4096
#define TTC   32          // chain time-tile
#define STT   64          // skip time-tile

typedef __attribute__((ext_vector_type(8))) short bf16x8;
typedef __attribute__((ext_vector_type(4))) float f32x4;

__device__ __forceinline__ unsigned short f2bf(float f) {
    union { float f; unsigned u; } v; v.f = f;
    return (unsigned short)((v.u + 0x7FFF + ((v.u >> 16) & 1)) >> 16);
}

// ---- weight prep: bf16 casts + dc-weight concat [o][kk] ----
__global__ __launch_bounds__(256) void prep_weights(
    const float* __restrict__ dc_w, const float* __restrict__ conv_w,
    const float* __restrict__ skip_w,
    unsigned short* __restrict__ wcat,  // [NBLK][64][128]
    unsigned short* __restrict__ cwb,   // [NBLK][64][64]
    unsigned short* __restrict__ swb)   // [NBLK][256][64]
{
    const int n_sw = NBLK * SCC * CC;
    const int n_cw = NBLK * CC * CC;
    const int n_wc = NBLK * CC * 128;
    for (int idx = blockIdx.x * blockDim.x + threadIdx.x; idx < n_sw;
         idx += gridDim.x * blockDim.x) {
        swb[idx] = f2bf(skip_w[idx]);
        if (idx < n_cw) cwb[idx] = f2bf(conv_w[idx]);
        if (idx < n_wc) {
            const int i = idx >> 13, o = (idx >> 7) & 63, kk = idx & 127;
            wcat[idx] = f2bf(dc_w[(((i * CC + o) * CC) + (kk & 63)) * 2 + (kk >> 6)]);
        }
    }
}

// ---- skip GEMM for one (b, 64t tile) of one block ----
__device__ __forceinline__ void skip_body(
    int id, const unsigned short* __restrict__ g,
    const unsigned short* __restrict__ sw, const float* __restrict__ sb,
    float* __restrict__ op)
{
    const int tid = threadIdx.x, lane = tid & 63, wv = tid >> 6;
    const int tt = id & 63;      // 64 tiles of 64 t
    const int b  = id >> 6;
    const unsigned short* gb = g + (size_t)b * SKIPN * CC;
    float* ob = op + (size_t)b * SCC * SKIPN;

    const int trow = tt * STT + wv * 16 + (lane & 15);
    bf16x8 a[2];
    #pragma unroll
    for (int ks = 0; ks < 2; ++ks)
        a[ks] = *(const bf16x8*)(gb + (size_t)trow * CC + ks * 32 + (lane >> 4) * 8);

    const int tstore = tt * STT + wv * 16 + ((lane >> 4) << 2);
    #pragma unroll 4
    for (int n = 0; n < 16; ++n) {
        const int sc = n * 16 + (lane & 15);
        const float bias = sb[sc];
        f32x4 acc = (f32x4){bias, bias, bias, bias};
        const unsigned short* wrow = sw + sc * CC + (lane >> 4) * 8;
        acc = __builtin_amdgcn_mfma_f32_16x16x32_bf16(a[0], *(const bf16x8*)(wrow), acc, 0, 0, 0);
        acc = __builtin_amdgcn_mfma_f32_16x16x32_bf16(a[1], *(const bf16x8*)(wrow + 32), acc, 0, 0, 0);
        *(float4*)(ob + (size_t)sc * SKIPN + tstore) = (float4){acc[0], acc[1], acc[2], acc[3]};
    }
}

// ---- one residual block step (+ fused prev-block skip role) ----
__global__ __launch_bounds__(256) void block_kernel(
    const float* __restrict__ cur, float* __restrict__ nxt,
    const unsigned short* __restrict__ wcat, const unsigned short* __restrict__ cwb,
    const float* __restrict__ db, const float* __restrict__ cb,
    unsigned short* __restrict__ g_out,
    int d, int Lin, int Lout, int ntiles,
    const unsigned short* __restrict__ g_prev,
    const unsigned short* __restrict__ swb_prev,
    const float* __restrict__ sb_prev,
    float* __restrict__ out_prev)
{
    const int wg = blockIdx.x;
    const int chain_wgs = BB * ntiles;
    if (wg >= chain_wgs) {                    // skip role for previous block
        skip_body(wg - chain_wgs, g_prev, swb_prev, sb_prev, out_prev);
        return;
    }

    __shared__ __align__(16) unsigned short xt[TTC * 128];   // [t][kk] swizzled, 8KB
    __shared__ __align__(16) unsigned short gs[TTC * CC];    // [t][o]  swizzled, 4KB
    __shared__ float x1f[CC][TTC + 1];                       // fp32 X1 stash, 8.25KB

    const int tid = threadIdx.x, lane = tid & 63, wv = tid >> 6;
    const int b  = wg / ntiles;
    const int t0 = (wg % ntiles) * TTC;
    const float* src = cur + (size_t)b * CC * LL0;

    // ---- stage X0 (kk=c) / X1 (kk=64+c) fp32 -> bf16 [t][kk]; X1 fp32 stash ----
    {
        const int c  = (tid & 31) * 2;       // channel pair
        const int tg = tid >> 5;             // 0..7 -> rows tg*4..tg*4+3
        const bool full = (t0 + TTC + d <= Lin);
        #pragma unroll
        for (int op = 0; op < 2; ++op) {
            const int doff = op ? d : 0;
            const int tb = t0 + tg * 4 + doff;
            float v0[4], v1[4];
            if (full && (op == 0 || (d & 3) == 0)) {
                *(float4*)v0 = *(const float4*)(src + (size_t)c * LL0 + tb);
                *(float4*)v1 = *(const float4*)(src + (size_t)(c + 1) * LL0 + tb);
            } else {
                #pragma unroll
                for (int j = 0; j < 4; ++j) {
                    int t = tb + j; if (t > Lin - 1) t = Lin - 1;
                    v0[j] = src[(size_t)c * LL0 + t];
                    v1[j] = src[(size_t)(c + 1) * LL0 + t];
                }
            }
            const int kk = op * 64 + c;
            const int chunk = kk >> 3, sub = kk & 7;
            #pragma unroll
            for (int j = 0; j < 4; ++j) {
                const int row = tg * 4 + j;
                const unsigned pack = (unsigned)f2bf(v0[j]) | ((unsigned)f2bf(v1[j]) << 16);
                *(unsigned*)((char*)xt + row * 256 + ((chunk ^ (row & 7)) * 16) + sub * 2) = pack;
            }
            if (op == 1) {
                #pragma unroll
                for (int j = 0; j < 4; ++j) {
                    x1f[c][tg * 4 + j]     = v0[j];
                    x1f[c + 1][tg * 4 + j] = v1[j];
                }
            }
        }
    }
    __syncthreads();

    const int rf = wv >> 1;   // t-row fragment (0..1)
    const int oh = wv & 1;    // o-half (0..1)

    // ---- GEMM1: H = Xcat . Wcat^T (+db), relu -> gs ----
    bf16x8 a1[4];
    {
        const int row = rf * 16 + (lane & 15);
        #pragma unroll
        for (int ks = 0; ks < 4; ++ks) {
            const int chunk = ks * 4 + (lane >> 4);
            a1[ks] = *(const bf16x8*)((const char*)xt + row * 256 + ((chunk ^ (row & 7)) * 16));
        }
    }
    f32x4 acc[2];
    #pragma unroll
    for (int n = 0; n < 2; ++n) {
        const int o = oh * 32 + n * 16 + (lane & 15);
        const float bias = db[o];
        acc[n] = (f32x4){bias, bias, bias, bias};
        const unsigned short* wrow = wcat + o * 128 + (lane >> 4) * 8;
        #pragma unroll
        for (int ks = 0; ks < 4; ++ks)
            acc[n] = __builtin_amdgcn_mfma_f32_16x16x32_bf16(
                a1[ks], *(const bf16x8*)(wrow + ks * 32), acc[n], 0, 0, 0);
    }
    {
        const int trow0 = rf * 16 + ((lane >> 4) << 2);
        #pragma unroll
        for (int n = 0; n < 2; ++n) {
            const int o = oh * 32 + n * 16 + (lane & 15);
            const int chunkb = o >> 3, sub = o & 7;
            #pragma unroll
            for (int r = 0; r < 4; ++r) {
                float g = acc[n][r]; g = g > 0.f ? g : 0.f;
                const int row = trow0 + r;
                *(unsigned short*)((char*)gs + row * 128 + ((chunkb ^ (row & 7)) * 16) + sub * 2) = f2bf(g);
            }
        }
    }
    __syncthreads();

    // ---- GEMM2 + residual (fp32 from LDS stash) + OUT store ----
    bf16x8 a2[2];
    {
        const int row = rf * 16 + (lane & 15);
        #pragma unroll
        for (int ks = 0; ks < 2; ++ks) {
            const int chunk = ks * 4 + (lane >> 4);
            a2[ks] = *(const bf16x8*)((const char*)gs + row * 128 + ((chunk ^ (row & 7)) * 16));
        }
    }
    {
        const int tloc = rf * 16 + ((lane >> 4) << 2);
        const int t = t0 + tloc;
        #pragma unroll
        for (int n = 0; n < 2; ++n) {
            const int o = oh * 32 + n * 16 + (lane & 15);
            const float bias = cb[o];
            f32x4 racc = (f32x4){bias, bias, bias, bias};
            const unsigned short* wrow = cwb + o * 64 + (lane >> 4) * 8;
            racc = __builtin_amdgcn_mfma_f32_16x16x32_bf16(a2[0], *(const bf16x8*)(wrow), racc, 0, 0, 0);
            racc = __builtin_amdgcn_mfma_f32_16x16x32_bf16(a2[1], *(const bf16x8*)(wrow + 32), racc, 0, 0, 0);
            float* outp = nxt + (size_t)b * CC * LL0 + (size_t)o * LL0 + t;
            if (t + 3 < Lout) {
                *(float4*)outp = (float4){racc[0] + x1f[o][tloc + 0],
                                          racc[1] + x1f[o][tloc + 1],
                                          racc[2] + x1f[o][tloc + 2],
                                          racc[3] + x1f[o][tloc + 3]};
            } else {
                #pragma unroll
                for (int r = 0; r < 4; ++r)
                    if (t + r < Lout) outp[r] = racc[r] + x1f[o][tloc + r];
            }
        }
    }

    // ---- store g window (bf16 [b][tw][64]) ----
    {
        const int skip_start = Lout - SKIPN;
        const int row = tid >> 3;            // 0..31
        const int ch  = tid & 7;             // logical 16B chunk
        const int t = t0 + row;
        if (t >= skip_start && t < Lout) {
            unsigned short* gr = g_out + ((size_t)b * SKIPN + (t - skip_start)) * CC;
            bf16x8 vv = *(const bf16x8*)((const char*)gs + row * 128 + ((ch ^ (row & 7)) * 16));
            *(bf16x8*)(gr + ch * 8) = vv;
        }
    }
}

// ---- standalone skip kernel (final block only) ----
__global__ __launch_bounds__(256) void skip_kernel(
    const unsigned short* __restrict__ g, const unsigned short* __restrict__ sw,
    const float* __restrict__ sb, float* __restrict__ op)
{
    skip_body(blockIdx.x, g, sw, sb, op);
}

extern "C" void kernel_launch(void* const* d_in, const int* in_sizes, int n_in,
                              void* d_out, int out_size, void* d_ws, size_t ws_size,
                              hipStream_t stream)
{
    const float* x      = (const float*)d_in[0];
    const float* dc_w   = (const float*)d_in[1];
    const float* dc_b   = (const float*)d_in[2];
    const float* conv_w = (const float*)d_in[3];
    const float* conv_b = (const float*)d_in[4];
    const float* skip_w = (const float*)d_in[5];
    const float* skip_b = (const float*)d_in[6];
    float* out = (float*)d_out;

    char* ws = (char*)d_ws;
    float* buf0 = (float*)ws;                    ws += (size_t)BB * CC * LL0 * 4;
    float* buf1 = (float*)ws;                    ws += (size_t)BB * CC * LL0 * 4;
    unsigned short* g_all = (unsigned short*)ws; ws += (size_t)NBLK * BB * SKIPN * CC * 2;
    unsigned short* wcat  = (unsigned short*)ws; ws += (size_t)NBLK * CC * 128 * 2;
    unsigned short* cwb   = (unsigned short*)ws; ws += (size_t)NBLK * CC * CC * 2;
    unsigned short* swb   = (unsigned short*)ws; ws += (size_t)NBLK * SCC * CC * 2;

    prep_weights<<<1024, 256, 0, stream>>>(dc_w, conv_w, skip_w, wcat, cwb, swb);

    const int skip_wgs = BB * (SKIPN / STT);   // 256
    int Lc = LL0;
    for (int i = 0; i < NBLK; ++i) {
        const int d = 1 << (i % 10);
        const int Lout = Lc - d;
        const int ntiles = (Lout + TTC - 1) / TTC;
        const float* curp = (i == 0) ? x : ((i & 1) ? buf0 : buf1);
        float*       nxtp = (i & 1) ? buf1 : buf0;
        const int j = i - 1;   // block whose skip GEMM rides along
        const int grid = BB * ntiles + (i ? skip_wgs : 0);
        block_kernel<<<dim3(grid), 256, 0, stream>>>(
            curp, nxtp,
            wcat + (size_t)i * CC * 128, cwb + (size_t)i * CC * CC,
            dc_b + i * CC, conv_b + i * CC,
            g_all + (size_t)i * BB * SKIPN * CC,
            d, Lc, Lout, ntiles,
            g_all + (size_t)(i ? j : 0) * BB * SKIPN * CC,
            swb + (size_t)(i ? j : 0) * SCC * CC,
            skip_b + (i ? j : 0) * SCC,
            out + (size_t)(i ? j : 0) * BB * SCC * SKIPN);
        Lc = Lout;
    }
    skip_kernel<<<dim3(skip_wgs), 256, 0, stream>>>(
        g_all + (size_t)(NBLK - 1) * BB * SKIPN * CC,
        swb + (size_t)(NBLK - 1) * SCC * CC,
        skip_b + (NBLK - 1) * SCC,
        out + (size_t)(NBLK - 1) * BB * SCC * SKIPN);
}

// Round 5
// 742.583 us; speedup vs baseline: 5.1391x; 1.1488x over previous
//
#include <hip/hip_runtime.h>

// WaveNet residual stack, MFMA bf16. Chain launches reduced 40 -> 20 by fusing
// the d=1..32 blocks of each stack into ONE kernel (halo-redundant tiles in
// LDS; stream [b][t][c] fp32, XOR-swizzled). d=64..512 remain single-block
// launches. Skip GEMMs ride as piggyback WGs on the following launch.

#define CC    64
#define SCC   256
#define BB    4
#define LL0   8192
#define NBLK  40
#define SKIPN 4096
#define TTC   32

typedef __attribute__((ext_vector_type(8))) short bf16x8;
typedef __attribute__((ext_vector_type(4))) float f32x4;

__device__ __forceinline__ unsigned short f2bf(float f) {
    union { float f; unsigned u; } v; v.f = f;
    return (unsigned short)((v.u + 0x7FFF + ((v.u >> 16) & 1)) >> 16);
}
__device__ __forceinline__ bf16x8 pack8(f32x4 u0, f32x4 u1) {
    bf16x8 r;
    r[0] = (short)f2bf(u0[0]); r[1] = (short)f2bf(u0[1]);
    r[2] = (short)f2bf(u0[2]); r[3] = (short)f2bf(u0[3]);
    r[4] = (short)f2bf(u1[0]); r[5] = (short)f2bf(u1[1]);
    r[6] = (short)f2bf(u1[2]); r[7] = (short)f2bf(u1[3]);
    return r;
}
// stream fp32 LDS word index, 32B-chunk XOR swizzle (c < 64)
__device__ __forceinline__ int sws(int row, int c) {
    return (row << 6) + (((((c >> 3) ^ row) & 7) << 3) | (c & 7));
}
// g bf16 LDS elem index (o < 64), 16B-chunk XOR swizzle
__device__ __forceinline__ int swg(int row, int o) {
    return (row << 6) + (((((o >> 3) ^ row) & 7) << 3) | (o & 7));
}
// xt bf16 LDS elem index (kk < 128), 16B-chunk XOR swizzle on low 3 chunk bits
__device__ __forceinline__ int swx(int row, int kk) {
    int ch = kk >> 3;
    ch = (ch & 8) | ((ch ^ row) & 7);
    return (row << 7) + (ch << 3) + (kk & 7);
}

// ---- weight prep: bf16 casts + dc-weight concat [o][kk] ----
__global__ __launch_bounds__(256) void prep_weights(
    const float* __restrict__ dc_w, const float* __restrict__ conv_w,
    const float* __restrict__ skip_w,
    unsigned short* __restrict__ wcat,  // [NBLK][64][128]
    unsigned short* __restrict__ cwb,   // [NBLK][64][64]
    unsigned short* __restrict__ swb)   // [NBLK][256][64]
{
    const int n_sw = NBLK * SCC * CC;
    const int n_cw = NBLK * CC * CC;
    const int n_wc = NBLK * CC * 128;
    for (int idx = blockIdx.x * blockDim.x + threadIdx.x; idx < n_sw;
         idx += gridDim.x * blockDim.x) {
        swb[idx] = f2bf(skip_w[idx]);
        if (idx < n_cw) cwb[idx] = f2bf(conv_w[idx]);
        if (idx < n_wc) {
            const int i = idx >> 13, o = (idx >> 7) & 63, kk = idx & 127;
            wcat[idx] = f2bf(dc_w[(((i * CC + o) * CC) + (kk & 63)) * 2 + (kk >> 6)]);
        }
    }
}

// ---- x [b][c][t] -> dst [b][t][c] fp32 ----
__global__ __launch_bounds__(256) void transpose_x(
    const float* __restrict__ x, float* __restrict__ dst)
{
    __shared__ float tile[64][65];
    const int b = blockIdx.y, t0 = blockIdx.x * 64;
    const int tid = threadIdx.x;
    #pragma unroll
    for (int p = 0; p < 4; ++p) {
        const int c = p * 16 + (tid >> 4);
        const int j = tid & 15;
        const float4 v = *(const float4*)(x + ((size_t)b * CC + c) * LL0 + t0 + j * 4);
        tile[c][j * 4 + 0] = v.x; tile[c][j * 4 + 1] = v.y;
        tile[c][j * 4 + 2] = v.z; tile[c][j * 4 + 3] = v.w;
    }
    __syncthreads();
    #pragma unroll
    for (int p = 0; p < 4; ++p) {
        const int r = p * 16 + (tid >> 4);
        const int h = tid & 15;
        float4 v = {tile[h * 4 + 0][r], tile[h * 4 + 1][r],
                    tile[h * 4 + 2][r], tile[h * 4 + 3][r]};
        *(float4*)(dst + ((size_t)b * LL0 + t0 + r) * CC + h * 4) = v;
    }
}

// ---- skip GEMM body; NW = waves per WG (tile rows = NW*16) ----
template<int NW>
__device__ __forceinline__ void skip_body(
    int e, int prev_blk0,
    const unsigned short* __restrict__ g_all,
    const unsigned short* __restrict__ swb,
    const float* __restrict__ skip_b, float* __restrict__ out)
{
    constexpr int ROWS = NW * 16;
    constexpr int TPB = (SKIPN / ROWS) * BB;
    const int tid = threadIdx.x, lane = tid & 63, wv = tid >> 6;
    const int j = prev_blk0 + e / TPB;
    const int id = e % TPB;
    const int tt = id % (SKIPN / ROWS);
    const int b  = id / (SKIPN / ROWS);
    const unsigned short* g = g_all + ((size_t)j * BB + b) * SKIPN * CC;
    const unsigned short* sw = swb + (size_t)j * SCC * CC;
    const float* sb = skip_b + j * SCC;
    float* op = out + ((size_t)j * BB + b) * SCC * SKIPN;

    const int trow = tt * ROWS + wv * 16 + (lane & 15);
    bf16x8 a[2];
    a[0] = *(const bf16x8*)(g + (size_t)trow * CC + (lane >> 4) * 8);
    a[1] = *(const bf16x8*)(g + (size_t)trow * CC + 32 + (lane >> 4) * 8);
    const int tstore = tt * ROWS + wv * 16 + ((lane >> 4) << 2);
    #pragma unroll 4
    for (int n = 0; n < 16; ++n) {
        const int sc = n * 16 + (lane & 15);
        const float bias = sb[sc];
        f32x4 acc = (f32x4){bias, bias, bias, bias};
        const unsigned short* wrow = sw + sc * CC + (lane >> 4) * 8;
        acc = __builtin_amdgcn_mfma_f32_16x16x32_bf16(a[0], *(const bf16x8*)(wrow), acc, 0, 0, 0);
        acc = __builtin_amdgcn_mfma_f32_16x16x32_bf16(a[1], *(const bf16x8*)(wrow + 32), acc, 0, 0, 0);
        *(float4*)(op + (size_t)sc * SKIPN + tstore) = (float4){acc[0], acc[1], acc[2], acc[3]};
    }
}

// ---- fused multi-block kernel (512 threads) ----
// NB blocks with d = DB<<j; LDS stream fp32 [row][c] swizzled, halo H=DB*(2^NB-1).
template<int NB, int DB, int TOUT, int R0CAP, int GSCAP, int MAXCH>
__global__ __launch_bounds__(512) void fused_kernel(
    const float* __restrict__ cur, float* __restrict__ nxt,
    const unsigned short* __restrict__ wcat_all, const unsigned short* __restrict__ cwb_all,
    const float* __restrict__ db_all, const float* __restrict__ cb_all,
    unsigned short* __restrict__ g_all, int blk0, int Lin, int ntiles,
    const unsigned short* __restrict__ swb, const float* __restrict__ skip_b,
    float* __restrict__ out, int prev_blk0, int prev_nblk)
{
    const int wg = blockIdx.x;
    const int chain = BB * ntiles;
    if (wg >= chain) {
        skip_body<8>(wg - chain, prev_blk0, g_all, swb, skip_b, out);
        return;
    }

    constexpr int H  = DB * ((1 << NB) - 1);
    constexpr int R0 = TOUT + H;
    __shared__ __align__(16) float sm[R0CAP * CC];
    __shared__ __align__(16) unsigned short gsm[GSCAP * CC];

    const int tid = threadIdx.x, lane = tid & 63, wv = tid >> 6;
    const int b = wg / ntiles, t0 = (wg % ntiles) * TOUT;
    const float* src = cur + (size_t)b * LL0 * CC;

    // ---- stage R0 rows of the stream (coalesced 256B/row) ----
    for (int base = 0; base < R0; base += 32) {
        const int row = base + (tid >> 4);
        const int h = tid & 15;
        if (row < R0) {
            int gt = t0 + row; if (gt > Lin - 1) gt = Lin - 1;
            *(f32x4*)(sm + sws(row, h * 4)) =
                *(const f32x4*)(src + (size_t)gt * CC + h * 4);
        }
    }
    __syncthreads();

    const int rf = wv >> 1, oh = wv & 1;   // 8 waves: 4 row-frags x 2 o-halves
    int Rcur = R0, Lj = Lin;

    for (int j = 0; j < NB; ++j) {
        const int d = DB << j;
        const int Rn = Rcur - d;
        Lj -= d;
        const unsigned short* wj  = wcat_all + (size_t)(blk0 + j) * CC * 128;
        const unsigned short* cj  = cwb_all + (size_t)(blk0 + j) * CC * CC;
        const float* dbj = db_all + (blk0 + j) * CC;
        const float* cbj = cb_all + (blk0 + j) * CC;

        // ---- phase 1: dilated conv GEMM + relu -> gsm ----
        #pragma unroll
        for (int ch = 0; ch < MAXCH; ++ch) {
            if (ch * 64 < Rn) {
                int row = ch * 64 + rf * 16 + (lane & 15);
                if (row > Rn - 1) row = Rn - 1;
                bf16x8 a1[4];
                #pragma unroll
                for (int ks = 0; ks < 2; ++ks) {
                    const int c0 = ks * 32 + (lane >> 4) * 8;
                    a1[ks] = pack8(*(const f32x4*)(sm + sws(row, c0)),
                                   *(const f32x4*)(sm + sws(row, c0 + 4)));
                    a1[2 + ks] = pack8(*(const f32x4*)(sm + sws(row + d, c0)),
                                       *(const f32x4*)(sm + sws(row + d, c0 + 4)));
                }
                f32x4 acc[2];
                #pragma unroll
                for (int n = 0; n < 2; ++n) {
                    const int o = oh * 32 + n * 16 + (lane & 15);
                    const float bias = dbj[o];
                    acc[n] = (f32x4){bias, bias, bias, bias};
                    const unsigned short* wrow = wj + o * 128 + (lane >> 4) * 8;
                    #pragma unroll
                    for (int ks = 0; ks < 4; ++ks)
                        acc[n] = __builtin_amdgcn_mfma_f32_16x16x32_bf16(
                            a1[ks], *(const bf16x8*)(wrow + ks * 32), acc[n], 0, 0, 0);
                }
                const int wr = ch * 64 + rf * 16 + ((lane >> 4) << 2);
                #pragma unroll
                for (int n = 0; n < 2; ++n) {
                    const int o = oh * 32 + n * 16 + (lane & 15);
                    #pragma unroll
                    for (int r = 0; r < 4; ++r) {
                        const int rr = wr + r;
                        if (rr < Rn) {
                            float g = acc[n][r]; g = g > 0.f ? g : 0.f;
                            gsm[swg(rr, o)] = f2bf(g);
                        }
                    }
                }
            }
        }
        __syncthreads();

        // ---- phase 2: 1x1 GEMM + residual source reads (no stream writes) ----
        f32x4 racc[MAXCH][2];
        f32x4 oldv[MAXCH][2];
        #pragma unroll
        for (int ch = 0; ch < MAXCH; ++ch) {
            if (ch * 64 < Rn) {
                int row = ch * 64 + rf * 16 + (lane & 15);
                if (row > Rn - 1) row = Rn - 1;
                bf16x8 a2[2];
                #pragma unroll
                for (int ks = 0; ks < 2; ++ks)
                    a2[ks] = *(const bf16x8*)(gsm + swg(row, ks * 32 + (lane >> 4) * 8));
                const int wr = ch * 64 + rf * 16 + ((lane >> 4) << 2);
                #pragma unroll
                for (int n = 0; n < 2; ++n) {
                    const int o = oh * 32 + n * 16 + (lane & 15);
                    const float bias = cbj[o];
                    racc[ch][n] = (f32x4){bias, bias, bias, bias};
                    const unsigned short* wrow = cj + o * CC + (lane >> 4) * 8;
                    racc[ch][n] = __builtin_amdgcn_mfma_f32_16x16x32_bf16(
                        a2[0], *(const bf16x8*)(wrow), racc[ch][n], 0, 0, 0);
                    racc[ch][n] = __builtin_amdgcn_mfma_f32_16x16x32_bf16(
                        a2[1], *(const bf16x8*)(wrow + 32), racc[ch][n], 0, 0, 0);
                    #pragma unroll
                    for (int r = 0; r < 4; ++r) {
                        int rr = wr + r; if (rr > Rn - 1) rr = Rn - 1;
                        oldv[ch][n][r] = sm[sws(rr + d, o)];
                    }
                }
            }
        }
        __syncthreads();

        // ---- phase 3: stream update + g window to global ----
        #pragma unroll
        for (int ch = 0; ch < MAXCH; ++ch) {
            if (ch * 64 < Rn) {
                const int wr = ch * 64 + rf * 16 + ((lane >> 4) << 2);
                #pragma unroll
                for (int n = 0; n < 2; ++n) {
                    const int o = oh * 32 + n * 16 + (lane & 15);
                    #pragma unroll
                    for (int r = 0; r < 4; ++r) {
                        const int rr = wr + r;
                        if (rr < Rn) sm[sws(rr, o)] = racc[ch][n][r] + oldv[ch][n][r];
                    }
                }
            }
        }
        {
            const int wbase = Lj - SKIPN;
            unsigned short* gdst = g_all + ((size_t)(blk0 + j) * BB + b) * SKIPN * CC;
            const int ch8 = tid & 7;
            for (int grow = tid >> 3; grow < Rn; grow += 64) {
                const int gt = t0 + grow;
                if (gt < Lj && gt >= wbase)
                    *(bf16x8*)(gdst + ((size_t)(gt - wbase)) * CC + ch8 * 8) =
                        *(const bf16x8*)(gsm + (grow << 6) + (((ch8 ^ grow) & 7) << 3));
            }
        }
        __syncthreads();
        Rcur = Rn;
    }

    // ---- final stream rows -> nxt ----
    float* dst = nxt + (size_t)b * LL0 * CC;
    for (int base = 0; base < TOUT; base += 32) {
        const int row = base + (tid >> 4);
        const int h = tid & 15;
        const int gt = t0 + row;
        if (row < TOUT && gt < Lj)
            *(float4*)(dst + (size_t)gt * CC + h * 4) =
                *(const float4*)(sm + sws(row, h * 4));
    }
}

// ---- single-block kernel (256 threads), stream [b][t][c] ----
__global__ __launch_bounds__(256) void block_kernel(
    const float* __restrict__ cur, float* __restrict__ nxt,
    const unsigned short* __restrict__ wcat, const unsigned short* __restrict__ cwb,
    const float* __restrict__ db, const float* __restrict__ cb,
    unsigned short* __restrict__ g_out,
    int d, int Lin, int Lout, int ntiles,
    const unsigned short* __restrict__ g_all, const unsigned short* __restrict__ swb,
    const float* __restrict__ skip_b, float* __restrict__ out,
    int prev_blk0, int prev_nblk)
{
    const int wg = blockIdx.x;
    const int chain = BB * ntiles;
    if (wg >= chain) {
        skip_body<4>(wg - chain, prev_blk0, g_all, swb, skip_b, out);
        return;
    }

    __shared__ __align__(16) unsigned short xt[TTC * 128];
    __shared__ __align__(16) unsigned short gs[TTC * CC];
    __shared__ float x1f[CC][TTC + 1];
    __shared__ __align__(16) float rs[TTC * CC];

    const int tid = threadIdx.x, lane = tid & 63, wv = tid >> 6;
    const int b = wg / ntiles, t0 = (wg % ntiles) * TTC;
    const float* src = cur + (size_t)b * LL0 * CC;

    // ---- stage both taps + fp32 x1 stash ----
    #pragma unroll
    for (int p = 0; p < 2; ++p) {
        const int row = p * 16 + (tid >> 4);
        const int h = tid & 15;
        int ta = t0 + row;     if (ta > Lin - 1) ta = Lin - 1;
        int tb = t0 + row + d; if (tb > Lin - 1) tb = Lin - 1;
        const float4 v0 = *(const float4*)(src + (size_t)ta * CC + h * 4);
        const float4 v1 = *(const float4*)(src + (size_t)tb * CC + h * 4);
        uint2 p0, p1;
        p0.x = (unsigned)f2bf(v0.x) | ((unsigned)f2bf(v0.y) << 16);
        p0.y = (unsigned)f2bf(v0.z) | ((unsigned)f2bf(v0.w) << 16);
        p1.x = (unsigned)f2bf(v1.x) | ((unsigned)f2bf(v1.y) << 16);
        p1.y = (unsigned)f2bf(v1.z) | ((unsigned)f2bf(v1.w) << 16);
        *(uint2*)(xt + swx(row, h * 4)) = p0;
        *(uint2*)(xt + swx(row, 64 + h * 4)) = p1;
        x1f[h * 4 + 0][row] = v1.x;
        x1f[h * 4 + 1][row] = v1.y;
        x1f[h * 4 + 2][row] = v1.z;
        x1f[h * 4 + 3][row] = v1.w;
    }
    __syncthreads();

    const int rf = wv >> 1, oh = wv & 1;
    const int row = rf * 16 + (lane & 15);

    // ---- GEMM1 + relu -> gs ----
    bf16x8 a1[4];
    #pragma unroll
    for (int ks = 0; ks < 4; ++ks)
        a1[ks] = *(const bf16x8*)(xt + swx(row, ks * 32 + (lane >> 4) * 8));
    f32x4 acc[2];
    #pragma unroll
    for (int n = 0; n < 2; ++n) {
        const int o = oh * 32 + n * 16 + (lane & 15);
        const float bias = db[o];
        acc[n] = (f32x4){bias, bias, bias, bias};
        const unsigned short* wrow = wcat + o * 128 + (lane >> 4) * 8;
        #pragma unroll
        for (int ks = 0; ks < 4; ++ks)
            acc[n] = __builtin_amdgcn_mfma_f32_16x16x32_bf16(
                a1[ks], *(const bf16x8*)(wrow + ks * 32), acc[n], 0, 0, 0);
    }
    const int wr = rf * 16 + ((lane >> 4) << 2);
    #pragma unroll
    for (int n = 0; n < 2; ++n) {
        const int o = oh * 32 + n * 16 + (lane & 15);
        #pragma unroll
        for (int r = 0; r < 4; ++r) {
            float g = acc[n][r]; g = g > 0.f ? g : 0.f;
            gs[swg(wr + r, o)] = f2bf(g);
        }
    }
    __syncthreads();

    // ---- GEMM2 + residual -> rs ----
    bf16x8 a2[2];
    #pragma unroll
    for (int ks = 0; ks < 2; ++ks)
        a2[ks] = *(const bf16x8*)(gs + swg(row, ks * 32 + (lane >> 4) * 8));
    #pragma unroll
    for (int n = 0; n < 2; ++n) {
        const int o = oh * 32 + n * 16 + (lane & 15);
        const float bias = cb[o];
        f32x4 racc = (f32x4){bias, bias, bias, bias};
        const unsigned short* wrow = cwb + o * CC + (lane >> 4) * 8;
        racc = __builtin_amdgcn_mfma_f32_16x16x32_bf16(a2[0], *(const bf16x8*)(wrow), racc, 0, 0, 0);
        racc = __builtin_amdgcn_mfma_f32_16x16x32_bf16(a2[1], *(const bf16x8*)(wrow + 32), racc, 0, 0, 0);
        #pragma unroll
        for (int r = 0; r < 4; ++r)
            rs[sws(wr + r, o)] = racc[r] + x1f[o][wr + r];
    }
    __syncthreads();

    // ---- coalesced out write + g window ----
    #pragma unroll
    for (int p = 0; p < 2; ++p) {
        const int row2 = p * 16 + (tid >> 4);
        const int h = tid & 15;
        const int t = t0 + row2;
        if (t < Lout)
            *(float4*)(nxt + (size_t)b * LL0 * CC + (size_t)t * CC + h * 4) =
                *(const float4*)(rs + sws(row2, h * 4));
    }
    {
        const int row2 = tid >> 3, ch8 = tid & 7;
        const int t = t0 + row2;
        const int wbase = Lout - SKIPN;
        if (t >= wbase && t < Lout)
            *(bf16x8*)(g_out + ((size_t)b * SKIPN + (t - wbase)) * CC + ch8 * 8) =
                *(const bf16x8*)(gs + (row2 << 6) + (((ch8 ^ row2) & 7) << 3));
    }
}

__global__ __launch_bounds__(256) void skip_kernel(
    const unsigned short* __restrict__ g_all, const unsigned short* __restrict__ swb,
    const float* __restrict__ skip_b, float* __restrict__ out, int blk)
{
    skip_body<4>(blockIdx.x, blk, g_all, swb, skip_b, out);
}

extern "C" void kernel_launch(void* const* d_in, const int* in_sizes, int n_in,
                              void* d_out, int out_size, void* d_ws, size_t ws_size,
                              hipStream_t stream)
{
    const float* x      = (const float*)d_in[0];
    const float* dc_w   = (const float*)d_in[1];
    const float* dc_b   = (const float*)d_in[2];
    const float* conv_w = (const float*)d_in[3];
    const float* conv_b = (const float*)d_in[4];
    const float* skip_w = (const float*)d_in[5];
    const float* skip_b = (const float*)d_in[6];
    float* out = (float*)d_out;

    char* ws = (char*)d_ws;
    float* bufA = (float*)ws;                    ws += (size_t)BB * LL0 * CC * 4;
    float* bufB = (float*)ws;                    ws += (size_t)BB * LL0 * CC * 4;
    unsigned short* g_all = (unsigned short*)ws; ws += (size_t)NBLK * BB * SKIPN * CC * 2;
    unsigned short* wcat  = (unsigned short*)ws; ws += (size_t)NBLK * CC * 128 * 2;
    unsigned short* cwb   = (unsigned short*)ws; ws += (size_t)NBLK * CC * CC * 2;
    unsigned short* swb   = (unsigned short*)ws; ws += (size_t)NBLK * SCC * CC * 2;

    prep_weights<<<1024, 256, 0, stream>>>(dc_w, conv_w, skip_w, wcat, cwb, swb);
    transpose_x<<<dim3(LL0 / 64, BB), 256, 0, stream>>>(x, bufA);

    float* bufs[2] = {bufA, bufB};
    int Lc = LL0, blk = 0, q = 0, pb0 = 0, pnb = 0;
    for (int s = 0; s < 4; ++s) {
        {   // fused d = 1..32 (6 blocks), T=96, LDS 61.4 KB
            const int Lout = Lc - 63;
            const int nt = (Lout + 95) / 96;
            const int grid = BB * nt + pnb * 128;
            fused_kernel<6, 1, 96, 160, 160, 3><<<dim3(grid), 512, 0, stream>>>(
                bufs[q & 1], bufs[(q + 1) & 1], wcat, cwb, dc_b, conv_b,
                g_all, blk, Lc, nt, swb, skip_b, out, pb0, pnb);
            pb0 = blk; pnb = 6; blk += 6; Lc = Lout; ++q;
        }
        for (int dl = 6; dl < 10; ++dl) {   // d = 64, 128, 256, 512 singles
            const int d = 1 << dl;
            const int Lout = Lc - d;
            const int nt = (Lout + TTC - 1) / TTC;
            const int grid = BB * nt + pnb * 256;
            block_kernel<<<dim3(grid), 256, 0, stream>>>(
                bufs[q & 1], bufs[(q + 1) & 1],
                wcat + (size_t)blk * CC * 128, cwb + (size_t)blk * CC * CC,
                dc_b + blk * CC, conv_b + blk * CC,
                g_all + (size_t)blk * BB * SKIPN * CC,
                d, Lc, Lout, nt,
                g_all, swb, skip_b, out, pb0, pnb);
            pb0 = blk; pnb = 1; blk += 1; Lc = Lout; ++q;
        }
    }
    skip_kernel<<<dim3(BB * (SKIPN / 64)), 256, 0, stream>>>(
        g_all, swb, skip_b, out, NBLK - 1);
}